// Round 8
// baseline (157.804 us; speedup 1.0000x reference)
//
#include <hip/hip_runtime.h>
#include <math.h>

#define N_ 16
#define C_ 4
#define F_ 257
#define T_ 1000
#define B_ 8
#define K_ 80
#define BK_ 640
#define TT_ 32
#define NT_ 32            // 32 t-tiles of 32 (covers 1024)
#define NBLK (N_ * NT_)   // 512 blocks
#define MSTR 260          // magS row stride (words)
#define WKS  80           // wT2 row stride: plain [f][k]

// d_ws byte offsets
#define WT_OFF   0                            // 257*80*4 = 82240 B
#define PART_OFF (128 * 1024)
#define SS_OFF   (PART_OFF + NBLK * 16 * 8)

// ---- transpose w_proj [k][f] -> wT2[f][k] ----
__global__ __launch_bounds__(80) void k_wt(const float* __restrict__ wp,
                                           float* __restrict__ wT) {
    int f = blockIdx.x;
    int k = threadIdx.x;
    wT[f * WKS + k] = wp[k * F_ + f];
}

// Fused beamform+mag (LDS) + projection GEMM (w via SCALAR loads) + relu+log
// + BN partial sums.  Block = (n, 32-t tile), all 8 b, all 80 k.
// GEMM roles: wave kg=tid>>6 owns 20 k's; lane: t_loc=tid&31, bh=(tid>>5)&1
//   -> thread tile = 4b x 20k x 1t = 80 acc; w loads are wave-uniform (SGPR).
// Staging roles: sfr=tid>>3 (f-row 0..31), stq=tid&7 (t-quad), all 8 b.
__global__ __launch_bounds__(256, 2) void k_fused(
    const float* __restrict__ xr, const float* __restrict__ xi,
    const float* __restrict__ wr, const float* __restrict__ wi,
    const float* __restrict__ wT,
    float* __restrict__ out, double* __restrict__ partials) {

    const int tid = threadIdx.x;
    const int bid = blockIdx.x;
    const int tt = bid & (NT_ - 1);
    const int n  = bid >> 5;
    const int t0 = tt * TT_;

    __shared__ float magS[TT_][MSTR];   // [t][f*8 + b]  33.3 KB
    __shared__ double redS1[4][2][4];
    __shared__ double redS2[4][2][4];

    const int t_loc = tid & 31;
    const int bh    = (tid >> 5) & 1;
    const int kg    = __builtin_amdgcn_readfirstlane(tid >> 6);  // wave-uniform

    const int sfr = tid >> 3;           // staging f-row
    const int stq = tid & 7;            // staging t-quad
    const int tb  = t0 + stq * 4;
    const bool tload = (tb + 4 <= T_);

    float acc[4][20];
#pragma unroll
    for (int jb = 0; jb < 4; ++jb)
#pragma unroll
        for (int j = 0; j < 20; ++j) acc[jb][j] = 0.f;

    const float* xrn = xr + (size_t)n * C_ * F_ * T_;
    const float* xin = xi + (size_t)n * C_ * F_ * T_;

    // -------- prefetch x for chunk 0 --------
    float4 pxr[C_], pxi[C_];
    if (tload) {
        const float* xrp = xrn + (size_t)sfr * T_ + tb;
        const float* xip = xin + (size_t)sfr * T_ + tb;
#pragma unroll
        for (int c = 0; c < C_; ++c) {
            pxr[c] = *(const float4*)(xrp + (size_t)c * F_ * T_);
            pxi[c] = *(const float4*)(xip + (size_t)c * F_ * T_);
        }
    }

    for (int ch = 0; ch < 8; ++ch) {
        const int f0 = ch * 32;
        const int f  = f0 + sfr;

        __syncthreads();   // previous GEMM done reading magS

        // ---- beamform mag into LDS: thread = (f-row sfr, t-quad stq) ----
        {
            float m[4][B_];
            if (tload) {
                float xrv[C_][4], xiv[C_][4];
#pragma unroll
                for (int c = 0; c < C_; ++c) {
                    xrv[c][0] = pxr[c].x; xrv[c][1] = pxr[c].y;
                    xrv[c][2] = pxr[c].z; xrv[c][3] = pxr[c].w;
                    xiv[c][0] = pxi[c].x; xiv[c][1] = pxi[c].y;
                    xiv[c][2] = pxi[c].z; xiv[c][3] = pxi[c].w;
                }
                const float* wrp = wr + (size_t)f * B_ * C_;
                const float* wip = wi + (size_t)f * B_ * C_;
#pragma unroll
                for (int b = 0; b < B_; ++b) {
                    float4 wrv = *(const float4*)(wrp + b * C_);
                    float4 wiv = *(const float4*)(wip + b * C_);
                    float wrc[4] = {wrv.x, wrv.y, wrv.z, wrv.w};
                    float wic[4] = {wiv.x, wiv.y, wiv.z, wiv.w};
#pragma unroll
                    for (int i = 0; i < 4; ++i) {
                        float br = 0.f, bi2 = 0.f;
#pragma unroll
                        for (int c = 0; c < C_; ++c) {
                            br  += xrv[c][i] * wrc[c] - xiv[c][i] * wic[c];
                            bi2 += xiv[c][i] * wrc[c] + xrv[c][i] * wic[c];
                        }
                        m[i][b] = sqrtf(br * br + bi2 * bi2 + 1e-5f);
                    }
                }
            } else {
#pragma unroll
                for (int i = 0; i < 4; ++i)
#pragma unroll
                    for (int b = 0; b < B_; ++b) m[i][b] = 0.f;
            }
#pragma unroll
            for (int i = 0; i < 4; ++i) {
                *(float4*)&magS[stq * 4 + i][sfr * 8] =
                    make_float4(m[i][0], m[i][1], m[i][2], m[i][3]);
                *(float4*)&magS[stq * 4 + i][sfr * 8 + 4] =
                    make_float4(m[i][4], m[i][5], m[i][6], m[i][7]);
            }
        }

        // ---- issue x prefetch for ch+1 ----
        if (ch < 7 && tload) {
            const float* xrp = xrn + (size_t)(f0 + 32 + sfr) * T_ + tb;
            const float* xip = xin + (size_t)(f0 + 32 + sfr) * T_ + tb;
#pragma unroll
            for (int c = 0; c < C_; ++c) {
                pxr[c] = *(const float4*)(xrp + (size_t)c * F_ * T_);
                pxi[c] = *(const float4*)(xip + (size_t)c * F_ * T_);
            }
        }

        __syncthreads();

        // ---- GEMM over 32 f rows: mag 1xb128 LDS, w scalar (SGPR) ----
        const float* wchunk = wT + (size_t)f0 * WKS + kg * 20;  // wave-uniform
#pragma unroll 2
        for (int fc = 0; fc < 32; ++fc) {
            float4 mv = *(const float4*)&magS[t_loc][fc * 8 + bh * 4];
            float wv[20];
#pragma unroll
            for (int j = 0; j < 20; ++j) wv[j] = wchunk[fc * WKS + j];
            float mbv[4] = {mv.x, mv.y, mv.z, mv.w};
#pragma unroll
            for (int jb = 0; jb < 4; ++jb)
#pragma unroll
                for (int j = 0; j < 20; ++j)
                    acc[jb][j] += mbv[jb] * wv[j];
        }
    }

    // ---- tail f = 256 ----
    __syncthreads();
    {
        int trow = tid >> 3;
        int b = tid & 7;
        int t = t0 + trow;
        float v = 0.f;
        if (t < T_) {
            const float* wrp = wr + (size_t)(256 * B_ + b) * C_;
            const float* wip = wi + (size_t)(256 * B_ + b) * C_;
            float br = 0.f, bi2 = 0.f;
#pragma unroll
            for (int c = 0; c < C_; ++c) {
                float xrv = xrn[((size_t)c * F_ + 256) * T_ + t];
                float xiv = xin[((size_t)c * F_ + 256) * T_ + t];
                br  += xrv * wrp[c] - xiv * wip[c];
                bi2 += xiv * wrp[c] + xrv * wip[c];
            }
            v = sqrtf(br * br + bi2 * bi2 + 1e-5f);
        }
        magS[trow][b] = v;
    }
    __syncthreads();
    {
        float4 mv = *(const float4*)&magS[t_loc][bh * 4];
        const float* wtail = wT + (size_t)256 * WKS + kg * 20;
        float mbv[4] = {mv.x, mv.y, mv.z, mv.w};
#pragma unroll
        for (int jb = 0; jb < 4; ++jb)
#pragma unroll
            for (int j = 0; j < 20; ++j)
                acc[jb][j] += mbv[jb] * wtail[j];
    }

    // ---- epilogue: relu+log, store (float4), per-b BN partial sums ----
    float s1f[4], s2f[4];
#pragma unroll
    for (int jb = 0; jb < 4; ++jb) { s1f[jb] = 0.f; s2f[jb] = 0.f; }
    const int t = t0 + t_loc;
    if (t < T_) {
        float* obase = out + ((size_t)n * T_ + t) * BK_ + (bh * 4) * K_ + kg * 20;
#pragma unroll
        for (int jb = 0; jb < 4; ++jb) {
            float vv[20];
#pragma unroll
            for (int j = 0; j < 20; ++j) {
                float v = fmaxf(acc[jb][j], 0.0f);
                v = __logf(v + 1e-5f);
                vv[j] = v;
                s1f[jb] += v;
                s2f[jb] += v * v;
            }
            float* orow = obase + jb * K_;
#pragma unroll
            for (int q = 0; q < 5; ++q)
                *(float4*)(orow + q * 4) =
                    make_float4(vv[q * 4], vv[q * 4 + 1], vv[q * 4 + 2], vv[q * 4 + 3]);
        }
    }
    const int wav = tid >> 6;
#pragma unroll
    for (int jb = 0; jb < 4; ++jb) {
        double d1 = (double)s1f[jb], d2 = (double)s2f[jb];
#pragma unroll
        for (int off = 16; off; off >>= 1) {   // xor-reduce within 32-lane half
            d1 += __shfl_xor(d1, off);
            d2 += __shfl_xor(d2, off);
        }
        if ((tid & 31) == 0) { redS1[wav][bh][jb] = d1; redS2[wav][bh][jb] = d2; }
    }
    __syncthreads();
    if (tid < 8) {
        int bh2 = tid >> 2, jb2 = tid & 3;
        partials[(size_t)bid * 16 + tid] =
            redS1[0][bh2][jb2] + redS1[1][bh2][jb2] + redS1[2][bh2][jb2] + redS1[3][bh2][jb2];
    } else if (tid >= 64 && tid < 72) {
        int id = tid - 64;
        int bh2 = id >> 2, jb2 = id & 3;
        partials[(size_t)bid * 16 + 8 + id] =
            redS2[0][bh2][jb2] + redS2[1][bh2][jb2] + redS2[2][bh2][jb2] + redS2[3][bh2][jb2];
    }
}

// ---------------- reduce partials -> per-channel scale/shift ----------------
__global__ __launch_bounds__(256) void k_bnstats(
    const double* __restrict__ partials,
    const float* __restrict__ gamma, const float* __restrict__ beta,
    float* __restrict__ ss) {
    const int b = threadIdx.x >> 5;
    const int i = threadIdx.x & 31;
    double s1 = 0.0, s2 = 0.0;
    for (int j = i; j < NBLK; j += 32) {
        s1 += partials[(size_t)j * 16 + b];
        s2 += partials[(size_t)j * 16 + 8 + b];
    }
#pragma unroll
    for (int off = 16; off; off >>= 1) {
        s1 += __shfl_down(s1, off);
        s2 += __shfl_down(s2, off);
    }
    if (i == 0) {
        const double cnt = (double)N_ * T_ * K_;
        double mean = s1 / cnt;
        double var = s2 / cnt - mean * mean;
        float scale = gamma[b] * (float)(1.0 / sqrt(var + 1e-5));
        float shift = beta[b] - (float)mean * scale;
        ss[b] = scale;
        ss[B_ + b] = shift;
    }
}

// ---------------- apply BN in place over d_out ----------------
__global__ __launch_bounds__(256) void k_bnapply(float* __restrict__ out,
                                                 const float* __restrict__ ss) {
    size_t i4 = (size_t)blockIdx.x * 256 + threadIdx.x;
    int k4 = (int)(i4 % (BK_ / 4));
    int b = k4 / (K_ / 4);
    float scale = ss[b], shift = ss[B_ + b];
    float4* p = (float4*)out + i4;
    float4 v = *p;
    v.x = v.x * scale + shift;
    v.y = v.y * scale + shift;
    v.z = v.z * scale + shift;
    v.w = v.w * scale + shift;
    *p = v;
}

extern "C" void kernel_launch(void* const* d_in, const int* in_sizes, int n_in,
                              void* d_out, int out_size, void* d_ws, size_t ws_size,
                              hipStream_t stream) {
    const float* xr = (const float*)d_in[0];
    const float* xi = (const float*)d_in[1];
    const float* wr = (const float*)d_in[2];
    const float* wi = (const float*)d_in[3];
    const float* w_proj = (const float*)d_in[4];
    const float* gamma = (const float*)d_in[5];
    const float* beta = (const float*)d_in[6];
    float* out = (float*)d_out;

    float* wT = (float*)((char*)d_ws + WT_OFF);
    double* partials = (double*)((char*)d_ws + PART_OFF);
    float* ss = (float*)((char*)d_ws + SS_OFF);

    k_wt<<<F_, 80, 0, stream>>>(w_proj, wT);
    k_fused<<<NBLK, 256, 0, stream>>>(xr, xi, wr, wi, wT, out, partials);
    k_bnstats<<<1, 256, 0, stream>>>(partials, gamma, beta, ss);
    k_bnapply<<<10000, 256, 0, stream>>>(out, ss);
}